// Round 4
// baseline (843.708 us; speedup 1.0000x reference)
//
#include <hip/hip_runtime.h>
#include <math.h>

// ---------------------------------------------------------------------------
// HybridBinaryClassifier360: conv1(3->6,5x5,s2,p1)+relu+maxpool2s1 ->
// conv2(6->15,3x3,s2,p1)+relu+maxpool2s1 -> fc 55815->120->84->1 ->
// RBF kernel vs 10 supports -> sigmoid -> [p, 1-p].  B=128, fp32.
//
// R13: conv1 = R11 work profile (3x staging, 30 accs) squeezed under 64
// VGPR for 8 blocks/CU. R12 proved oc-split buys occupancy but doubles
// staging work (FETCH 77->154MB, conv1 94->113us). Instead: (a) staging
// keeps only vv[4]+ladr[4] live (LDS addr precomputed, indices dropped),
// (b) compute uses a 7-float rolling window (dc-outer: dc needs
// v[2dc..2dc+4], slide by 2) instead of 13 live, (c) epilogue index math
// sunk below the loop. Live set ~45 -> __launch_bounds__(256,8) pin (64-reg
// budget) has slack, unlike R10 where live 67+ > 64 caused the spill storm.
// LDS 19.8KB x 8 = 158.7KB -> 8 blocks/CU, 2048-block grid = one round.
// conv2/fc1/reduce/head unchanged from R11/R12.
// ---------------------------------------------------------------------------

#define BATCH 128

// ---------------- Kernel 1: conv1 + relu + maxpool(2,s1) -------------------
// x [128,3,250,250] -> pool1 [128,6,123,123]
// tile: 31 pooled rows x 32 pooled cols; block 256 = 32 rowgroups(x1 conv
// row) x 8 strips(x4 pooled cols). Per-ci LDS slice [67][74] (69 cols used,
// skew il+(il>>4)) = 19.8KB. cbuf (wave-boundary exchange) 3x8x30 floats,
// unioned into the slice. grid (4, 4, 128).
// Magic div: i/69 = (i*121575)>>23 (valid i < 125203).
#define C1_ST 74
#define C1_COLS 69
#define C1_ROWS 67
#define C1_TOT (C1_ROWS * C1_COLS)   // 4623
__global__ __launch_bounds__(256, 8) void conv1_pool_kernel(
    const float* __restrict__ x, const float* __restrict__ w,
    const float* __restrict__ bias, float* __restrict__ out) {
  const int b = blockIdx.z;
  const int P0 = blockIdx.x * 32;    // first pooled col
  const int R0 = blockIdx.y * 31;    // first pooled row
  const int tid = threadIdx.x;
  const int t = tid >> 3;            // rowgroup 0..31 (conv row R0+t)
  const int s = tid & 7;             // strip 0..7 (4 pooled cols)

  __shared__ float lds[C1_ROWS * C1_ST];   // 4958 floats = 19832 B
  float* cbuf = lds;                 // exchange reuses [0,720) after compute

  float acc[5][6];                   // [conv col dc][oc]
#pragma unroll
  for (int oc = 0; oc < 6; oc++) {
    float bv = bias[oc];
#pragma unroll
    for (int dc = 0; dc < 5; dc++) acc[dc][oc] = bv;
  }

  const int ihb = 2 * R0 - 1, iwb = 2 * P0 - 1;
  // LDS read bases (skew il+(il>>4); il = 8s+j; carry for j>=8 when s odd
  // folded into a second base so ds offsets are immediates)
  const float* rbase = &lds[(2 * t) * C1_ST + 8 * s + (s >> 1)];
  const int hfix = s & 1;

#pragma unroll 1
  for (int ci = 0; ci < 3; ci++) {
    __syncthreads();                 // WAR: previous ci's compute done
    const float* src = x + (size_t)(b * 3 + ci) * 62500;
#pragma unroll 1
    for (int base = tid; base < C1_TOT; base += 1024) {
      float vv[4];
      int ladr[4];
#pragma unroll
      for (int k = 0; k < 4; k++) {
        int i = base + (k << 8);
        int lr = (int)(((unsigned)i * 121575u) >> 23);  // i / 69
        int il = i - lr * 69;                           // i % 69
        int ih = ihb + lr, iw = iwb + il;
        bool ok = (i < C1_TOT) && ((unsigned)ih < 250u) && ((unsigned)iw < 250u);
        vv[k] = ok ? src[ih * 250 + iw] : 0.f;
        ladr[k] = (i < C1_TOT) ? (lr * C1_ST + il + (il >> 4)) : -1;
      }
#pragma unroll
      for (int k = 0; k < 4; k++) {
        if (ladr[k] >= 0) lds[ladr[k]] = vv[k];
      }
    }
    __syncthreads();                 // RAW: staging visible

    // input slice rows for this conv row: 2t + ir, ir = 0..4 (kh).
    // Rolling 5+2 window: dc uses v[2dc..2dc+4]; slide by 2 per dc.
#pragma unroll
    for (int ir = 0; ir < 5; ir++) {
      const float* rpl = rbase + ir * C1_ST;
      const float* rph = rpl + hfix;          // base for j >= 8
      float va = rpl[0], vb = rpl[1], vc = rpl[2], vd = rpl[3], ve = rpl[4];
#pragma unroll
      for (int dc = 0; dc < 5; dc++) {
#pragma unroll
        for (int oc = 0; oc < 6; oc++) {
          const float* wr = w + ((oc * 3 + ci) * 5 + ir) * 5;
          float a = acc[dc][oc];
          a += wr[0] * va;
          a += wr[1] * vb;
          a += wr[2] * vc;
          a += wr[3] * vd;
          a += wr[4] * ve;
          acc[dc][oc] = a;
        }
        if (dc < 4) {
          const int j5 = 2 * dc + 5, j6 = 2 * dc + 6;
          float vn1 = (j5 < 8) ? rpl[j5] : rph[j5];
          float vn2 = (j6 < 8) ? rpl[j6] : rph[j6];
          va = vc; vb = vd; vc = ve; vd = vn1; ve = vn2;
        }
      }
    }
  }

  // ---- wave-boundary exchange: conv rows 8/16/24 publish for t=7/15/23 ----
  __syncthreads();                   // all compute done; input slice dead
  if (t == 8 || t == 16 || t == 24) {
    float* cb = &cbuf[(((t >> 3) - 1) * 8 + s) * 30];
#pragma unroll
    for (int oc = 0; oc < 6; oc++)
#pragma unroll
      for (int dc = 0; dc < 5; dc++) cb[oc * 5 + dc] = acc[dc][oc];
  }
  __syncthreads();                   // cbuf visible

  // ---- pooled row p0 = R0+t = max(conv t [own], conv t+1 [lane+8]) ----
  const int p0 = R0 + t;
  const int c0 = P0 + 4 * s;
  const bool edge = ((t & 7) == 7) && (t < 31);   // neighbor is cross-wave
  const bool wr_ok = (t < 31) && (p0 < 123);
  const float* cb = &cbuf[((t >> 3) * 8 + s) * 30];

#pragma unroll
  for (int oc = 0; oc < 6; oc++) {
    float a0 = acc[0][oc], a1 = acc[1][oc], a2 = acc[2][oc],
          a3 = acc[3][oc], a4 = acc[4][oc];
    // shuffles issued by ALL lanes (sources must be active)
    float n0 = __shfl_down(a0, 8), n1 = __shfl_down(a1, 8),
          n2 = __shfl_down(a2, 8), n3 = __shfl_down(a3, 8),
          n4 = __shfl_down(a4, 8);
    if (edge) {
      n0 = cb[oc * 5 + 0]; n1 = cb[oc * 5 + 1]; n2 = cb[oc * 5 + 2];
      n3 = cb[oc * 5 + 3]; n4 = cb[oc * 5 + 4];
    }
    if (wr_ok) {
      float* orow = out + ((size_t)(b * 6 + oc) * 123 + p0) * 123;
      float m0 = fmaxf(fmaxf(fmaxf(a0, a1), fmaxf(n0, n1)), 0.f);
      float m1 = fmaxf(fmaxf(fmaxf(a1, a2), fmaxf(n1, n2)), 0.f);
      float m2 = fmaxf(fmaxf(fmaxf(a2, a3), fmaxf(n2, n3)), 0.f);
      float m3 = fmaxf(fmaxf(fmaxf(a3, a4), fmaxf(n3, n4)), 0.f);
      if (c0 + 3 < 123) {
        *(float4*)&orow[c0] = make_float4(m0, m1, m2, m3);
      } else {
        if (c0 < 123) orow[c0] = m0;
        if (c0 + 1 < 123) orow[c0 + 1] = m1;
        if (c0 + 2 < 123) orow[c0 + 2] = m2;
      }
    }
  }
}

// ---------------- Kernel 2: conv2 + relu + maxpool(2,s1) -------------------
// pool1 [128,6,123,123] -> act [128, 15*61*61] (NCHW flatten)
// (unchanged)
#define C2_ST 84
#define C2_TOT (35 * 67)    // 2345
__global__ __launch_bounds__(256) void conv2_pool_kernel(
    const float* __restrict__ in, const float* __restrict__ w,
    const float* __restrict__ bias, float* __restrict__ out) {
  const int b = blockIdx.z;
  const int P0 = blockIdx.x * 32;
  const int R0 = blockIdx.y * 16;
  const int tid = threadIdx.x;
  const int t = tid >> 4;           // pooled row 0..15
  const int s = tid & 15;           // strip 0..15 (2 pooled cols)

  __shared__ float lds[35 * C2_ST];

  const int ihb = 2 * R0 - 1, iwb = 2 * P0 - 1;
  const int r = R0 + t;
  const int c0 = P0 + 2 * s;

#pragma unroll 1
  for (int ocg = 0; ocg < 2; ocg++) {
    const int oc0 = ocg * 7;        // {0..7}, {7..14}
    float acc0[3][8], acc1[3][8];
#pragma unroll
    for (int k = 0; k < 8; k++) {
      float bv = bias[oc0 + k];
#pragma unroll
      for (int dc = 0; dc < 3; dc++) { acc0[dc][k] = bv; acc1[dc][k] = bv; }
    }

#pragma unroll 1
    for (int ci = 0; ci < 6; ci++) {
      __syncthreads();               // WAR
      const float* src = in + (size_t)(b * 6 + ci) * 15129;  // 123*123
#pragma unroll 1
      for (int base = tid; base < C2_TOT; base += 2048) {
        float vv[8];
        int lrv[8], ilv[8];
#pragma unroll
        for (int k = 0; k < 8; k++) {
          int i = base + (k << 8);
          int lr = (int)(((unsigned)i * 125204u) >> 23);  // i / 67
          int il = i - lr * 67;                           // i % 67
          lrv[k] = lr; ilv[k] = il;
          int ih = ihb + lr, iw = iwb + il;
          bool ok = (i < C2_TOT) && ((unsigned)ih < 123u) && ((unsigned)iw < 123u);
          vv[k] = ok ? src[ih * 123 + iw] : 0.f;
        }
#pragma unroll
        for (int k = 0; k < 8; k++) {
          int i = base + (k << 8);
          if (i < C2_TOT) lds[lrv[k] * C2_ST + ilv[k] + (ilv[k] >> 2)] = vv[k];
        }
      }
      __syncthreads();               // RAW

#pragma unroll 1
      for (int ir = 0; ir < 5; ir++) {
        const float* rp = &lds[(2 * t + ir) * C2_ST + 5 * s];
        float v[7];
#pragma unroll
        for (int j = 0; j < 7; j++) v[j] = rp[j + (j >> 2)];

        if (ir < 3) {                // conv row r, kh = ir
#pragma unroll
          for (int k = 0; k < 8; k++) {
            const float* wr = w + (((oc0 + k) * 6 + ci) * 3 + ir) * 3;
            float w0 = wr[0], w1 = wr[1], w2 = wr[2];
#pragma unroll
            for (int dc = 0; dc < 3; dc++) {
              float a = acc0[dc][k];
              a += w0 * v[2 * dc + 0];
              a += w1 * v[2 * dc + 1];
              a += w2 * v[2 * dc + 2];
              acc0[dc][k] = a;
            }
          }
        }
        if (ir >= 2) {               // conv row r+1, kh = ir-2
#pragma unroll
          for (int k = 0; k < 8; k++) {
            const float* wr = w + (((oc0 + k) * 6 + ci) * 3 + (ir - 2)) * 3;
            float w0 = wr[0], w1 = wr[1], w2 = wr[2];
#pragma unroll
            for (int dc = 0; dc < 3; dc++) {
              float a = acc1[dc][k];
              a += w0 * v[2 * dc + 0];
              a += w1 * v[2 * dc + 1];
              a += w2 * v[2 * dc + 2];
              acc1[dc][k] = a;
            }
          }
        }
      }
    }

    if (r < 61) {
#pragma unroll
      for (int k = 0; k < 8; k++) {
        int oc = oc0 + k;
        float* orow = out + ((size_t)(b * 15 + oc) * 61 + r) * 61;
        float m0 = fmaxf(fmaxf(fmaxf(acc0[0][k], acc0[1][k]),
                               fmaxf(acc1[0][k], acc1[1][k])), 0.f);
        float m1 = fmaxf(fmaxf(fmaxf(acc0[1][k], acc0[2][k]),
                               fmaxf(acc1[1][k], acc1[2][k])), 0.f);
        if (c0 + 1 < 61) {
          *(float2*)&orow[c0] = make_float2(m0, m1);
        } else if (c0 < 61) {
          orow[c0] = m0;
        }
      }
    }
  }
}

// ---------------- Kernel 3: fc1 split-K GEMM partials ----------------------
// (unchanged)
#define KTOT 55815
#define NPART 512
#define KCHUNK 112
__global__ __launch_bounds__(512) void fc1_splitk_kernel(
    const float* __restrict__ act, const float* __restrict__ w,
    float* __restrict__ partial) {
  const int kbase = blockIdx.x * KCHUNK;
  const int tid = threadIdx.x;
  const int tx = tid & 31, ty = tid >> 5;
  __shared__ float ldsA[8 * 132];
  __shared__ float ldsB[8 * 132];
  float acc[8][4];
#pragma unroll
  for (int i = 0; i < 8; i++)
#pragma unroll
    for (int j = 0; j < 4; j++) acc[i][j] = 0.f;

  for (int s8 = 0; s8 < KCHUNK / 8; s8++) {
    int kofs = kbase + s8 * 8;
    __syncthreads();
    for (int i = tid; i < 1024; i += 512) {
      int m = i >> 3, kk = i & 7;
      int k = kofs + kk;
      ldsA[kk * 132 + m] = (k < KTOT) ? act[m * KTOT + k] : 0.f;
    }
    for (int i = tid; i < 960; i += 512) {
      int n = i >> 3, kk = i & 7;
      int k = kofs + kk;
      ldsB[kk * 132 + n] = (k < KTOT) ? w[n * KTOT + k] : 0.f;
    }
    __syncthreads();
#pragma unroll
    for (int kk = 0; kk < 8; kk++) {
      float4 a0 = *(const float4*)&ldsA[kk * 132 + ty * 8];
      float4 a1 = *(const float4*)&ldsA[kk * 132 + ty * 8 + 4];
      float4 b0 = *(const float4*)&ldsB[kk * 132 + tx * 4];
      float av[8] = {a0.x, a0.y, a0.z, a0.w, a1.x, a1.y, a1.z, a1.w};
      float bv[4] = {b0.x, b0.y, b0.z, b0.w};
#pragma unroll
      for (int i = 0; i < 8; i++)
#pragma unroll
        for (int j = 0; j < 4; j++) acc[i][j] += av[i] * bv[j];
    }
  }

  if (tx < 30) {
    float* dst = partial + (size_t)blockIdx.x * 15360;
#pragma unroll
    for (int i = 0; i < 8; i++) {
      int row = ty * 8 + i;
      float4 st = make_float4(acc[i][0], acc[i][1], acc[i][2], acc[i][3]);
      *(float4*)&dst[row * 120 + tx * 4] = st;
    }
  }
}

// ---------------- Kernel 4a/4b: two-stage reduce + bias + relu -------------
__global__ __launch_bounds__(64) void fc1_reduce1_kernel(
    const float* __restrict__ partial, float* __restrict__ partial2) {
  int idx = blockIdx.x * 64 + threadIdx.x;   // 0..15359
  int g = blockIdx.y;                        // 0..7
  const float* p = partial + (size_t)g * 64 * 15360 + idx;
  float s = 0.f;
#pragma unroll 8
  for (int q = 0; q < 64; q++) s += p[(size_t)q * 15360];
  partial2[(size_t)g * 15360 + idx] = s;
}

__global__ __launch_bounds__(64) void fc1_reduce2_kernel(
    const float* __restrict__ partial2, const float* __restrict__ bias,
    float* __restrict__ h1) {
  int idx = blockIdx.x * 64 + threadIdx.x;
  float s = 0.f;
#pragma unroll
  for (int g = 0; g < 8; g++) s += partial2[(size_t)g * 15360 + idx];
  h1[idx] = fmaxf(s + bias[idx % 120], 0.f);
}

// ---------------- Kernel 5: fc2 + fc3 + RBF + sigmoid ----------------------
__global__ __launch_bounds__(128) void head_kernel(
    const float* __restrict__ h1, const float* __restrict__ fc2_w,
    const float* __restrict__ fc2_b, const float* __restrict__ fc3_w,
    const float* __restrict__ fc3_b, const float* __restrict__ support,
    float* __restrict__ out) {
  int b = blockIdx.x, t = threadIdx.x;
  __shared__ float hrow[120];
  __shared__ float s2[84];
  if (t < 120) hrow[t] = h1[b * 120 + t];
  __syncthreads();
  if (t < 84) {
    float d = fc2_b[t];
    for (int k = 0; k < 120; k++) d += fc2_w[t * 120 + k] * hrow[k];
    s2[t] = fmaxf(d, 0.f);
  }
  __syncthreads();
  if (t == 0) {
    float h = fc3_b[0];
    for (int j = 0; j < 84; j++) h += fc3_w[j] * s2[j];
    float ks = 0.f;
    for (int j = 0; j < 10; j++) {
      float diff = h - support[j];
      ks += expf(-diff * diff);
    }
    ks *= 0.1f;
    float p = 1.f / (1.f + expf(-ks));
    out[b * 2] = p;
    out[b * 2 + 1] = 1.f - p;
  }
}

// ---------------------------------------------------------------------------
extern "C" void kernel_launch(void* const* d_in, const int* in_sizes, int n_in,
                              void* d_out, int out_size, void* d_ws, size_t ws_size,
                              hipStream_t stream) {
  const float* x   = (const float*)d_in[0];
  const float* c1w = (const float*)d_in[1];
  const float* c1b = (const float*)d_in[2];
  const float* c2w = (const float*)d_in[3];
  const float* c2b = (const float*)d_in[4];
  const float* f1w = (const float*)d_in[5];
  const float* f1b = (const float*)d_in[6];
  const float* f2w = (const float*)d_in[7];
  const float* f2b = (const float*)d_in[8];
  const float* f3w = (const float*)d_in[9];
  const float* f3b = (const float*)d_in[10];
  const float* sup = (const float*)d_in[11];
  float* out = (float*)d_out;

  char* ws = (char*)d_ws;
  // Lifetimes: pool1 [0,46.5MB) dead after conv2 -> part/part2/h1 reuse it.
  float* pool1 = (float*)ws;                     // 46,476,288 B
  float* act   = (float*)(ws + 46476288);        // 28,577,280 B (alive thru fc1)
  float* part  = (float*)ws;                     // 512*15360*4 = 31,457,280 B
  float* h1    = (float*)(ws + 33000000);        //     61,440 B
  float* part2 = (float*)(ws + 34000000);        //  8*15360*4 = 491,520 B

  conv1_pool_kernel<<<dim3(4, 4, BATCH), 256, 0, stream>>>(x, c1w, c1b, pool1);
  conv2_pool_kernel<<<dim3(2, 4, BATCH), 256, 0, stream>>>(pool1, c2w, c2b, act);
  fc1_splitk_kernel<<<NPART, 512, 0, stream>>>(act, f1w, part);
  fc1_reduce1_kernel<<<dim3(240, 8), 64, 0, stream>>>(part, part2);
  fc1_reduce2_kernel<<<240, 64, 0, stream>>>(part2, f1b, h1);
  head_kernel<<<BATCH, 128, 0, stream>>>(h1, f2w, f2b, f3w, f3b, sup, out);
}

// Round 5
// 349.834 us; speedup vs baseline: 2.4117x; 2.4117x over previous
//
#include <hip/hip_runtime.h>
#include <math.h>

// ---------------------------------------------------------------------------
// HybridBinaryClassifier360: conv1(3->6,5x5,s2,p1)+relu+maxpool2s1 ->
// conv2(6->15,3x3,s2,p1)+relu+maxpool2s1 -> fc 55815->120->84->1 ->
// RBF kernel vs 10 supports -> sigmoid -> [p, 1-p].  B=128, fp32.
//
// R14: conv1 = R11 (known-good 94us, 76 VGPR, NO launch-bounds pin -- the
// (256,8) pin collapsed the allocator to 32 VGPR and spilled 2.4GB twice,
// R10/R13) with ONE constant fix: LDS stride 74->78, skew >>4 -> >>3.
// R11's read bank map (20t+8s+(s>>1)+j)%32 was 4-way conflicted (4.08M
// conflict cycles measured); (28t+9s+j)%32 is exactly 2 lanes/bank = free.
// Also: fc1_reduce1+reduce2 fused into one kernel (saves a launch + the
// part2 round-trip). conv2/fc1_splitk/head unchanged.
// ---------------------------------------------------------------------------

#define BATCH 128

// ---------------- Kernel 1: conv1 + relu + maxpool(2,s1) -------------------
// x [128,3,250,250] -> pool1 [128,6,123,123]
// tile: 31 pooled rows x 32 pooled cols; block 256 = 32 rowgroups(x1 conv
// row) x 8 strips(x4 pooled cols). Per-ci LDS slice [67][78] (69 cols used,
// skew il+(il>>3); read banks (28t+9s+j)%32 = exact 2-way = free) = 20.9KB.
// cbuf (wave-boundary exchange) 3x8x30 floats, unioned into the slice.
// grid (4, 4, 128). Magic div: i/69 = (i*121575)>>23 (valid i < 125203).
#define C1_ST 78
#define C1_COLS 69
#define C1_ROWS 67
#define C1_TOT (C1_ROWS * C1_COLS)   // 4623
__global__ __launch_bounds__(256) void conv1_pool_kernel(
    const float* __restrict__ x, const float* __restrict__ w,
    const float* __restrict__ bias, float* __restrict__ out) {
  const int b = blockIdx.z;
  const int P0 = blockIdx.x * 32;    // first pooled col
  const int R0 = blockIdx.y * 31;    // first pooled row
  const int tid = threadIdx.x;
  const int t = tid >> 3;            // rowgroup 0..31 (conv row R0+t)
  const int s = tid & 7;             // strip 0..7 (4 pooled cols)

  __shared__ float lds[C1_ROWS * C1_ST];   // 5226 floats = 20904 B
  float* cbuf = lds;                 // exchange reuses [0,720) after compute

  float acc[5][6];                   // conv row R0+t x 5 conv cols x 6 oc
#pragma unroll
  for (int oc = 0; oc < 6; oc++) {
    float bv = bias[oc];
#pragma unroll
    for (int dc = 0; dc < 5; dc++) acc[dc][oc] = bv;
  }

  const int ihb = 2 * R0 - 1, iwb = 2 * P0 - 1;

#pragma unroll 1
  for (int ci = 0; ci < 3; ci++) {
    __syncthreads();                 // WAR: previous ci's compute done
    const float* src = x + (size_t)(b * 3 + ci) * 62500;
#pragma unroll 1
    for (int base = tid; base < C1_TOT; base += 1024) {
      float vv[4];
      int lrv[4], ilv[4];
#pragma unroll
      for (int k = 0; k < 4; k++) {
        int i = base + (k << 8);
        int lr = (int)(((unsigned)i * 121575u) >> 23);  // i / 69
        int il = i - lr * 69;                           // i % 69
        lrv[k] = lr; ilv[k] = il;
        int ih = ihb + lr, iw = iwb + il;
        bool ok = (i < C1_TOT) && ((unsigned)ih < 250u) && ((unsigned)iw < 250u);
        vv[k] = ok ? src[ih * 250 + iw] : 0.f;
      }
#pragma unroll
      for (int k = 0; k < 4; k++) {
        int i = base + (k << 8);
        if (i < C1_TOT) lds[lrv[k] * C1_ST + ilv[k] + (ilv[k] >> 3)] = vv[k];
      }
    }
    __syncthreads();                 // RAW: staging visible

    // input slice rows for this thread's conv row: 2t + ir, ir = 0..4 (kh)
    // col map: addr = il + (il>>3), il = 8s+j -> 9s + j for j<8,
    // 9s + j + 1 for j=8..12 (uniform +1, no per-lane fixup).
    const float* rbase = &lds[(2 * t) * C1_ST + 9 * s];
#pragma unroll
    for (int ir = 0; ir < 5; ir++) {
      const float* rpl = rbase + ir * C1_ST;
      const float* rph = rpl + 1;
      float v[13];
#pragma unroll
      for (int j = 0; j < 8; j++)  v[j] = rpl[j];
#pragma unroll
      for (int j = 8; j < 13; j++) v[j] = rph[j];
#pragma unroll
      for (int oc = 0; oc < 6; oc++) {
        const float* wr = w + ((oc * 3 + ci) * 5 + ir) * 5;
        float w0 = wr[0], w1 = wr[1], w2 = wr[2], w3 = wr[3], w4 = wr[4];
#pragma unroll
        for (int dc = 0; dc < 5; dc++) {
          float a = acc[dc][oc];
          a += w0 * v[2 * dc + 0];
          a += w1 * v[2 * dc + 1];
          a += w2 * v[2 * dc + 2];
          a += w3 * v[2 * dc + 3];
          a += w4 * v[2 * dc + 4];
          acc[dc][oc] = a;
        }
      }
    }
  }

  // ---- wave-boundary exchange: conv rows 8/16/24 publish for t=7/15/23 ----
  __syncthreads();                   // all compute done; input slice dead
  if (t == 8 || t == 16 || t == 24) {
    float* cb = &cbuf[(((t >> 3) - 1) * 8 + s) * 30];
#pragma unroll
    for (int oc = 0; oc < 6; oc++)
#pragma unroll
      for (int dc = 0; dc < 5; dc++) cb[oc * 5 + dc] = acc[dc][oc];
  }
  __syncthreads();                   // cbuf visible

  // ---- pooled row p0 = R0+t = max(conv t [own], conv t+1 [lane+8]) ----
  const int p0 = R0 + t;
  const int c0 = P0 + 4 * s;
  const bool edge = ((t & 7) == 7) && (t < 31);   // neighbor is cross-wave
  const bool wr_ok = (t < 31) && (p0 < 123);
  const float* cb = &cbuf[((t >> 3) * 8 + s) * 30];

#pragma unroll
  for (int oc = 0; oc < 6; oc++) {
    float a0 = acc[0][oc], a1 = acc[1][oc], a2 = acc[2][oc],
          a3 = acc[3][oc], a4 = acc[4][oc];
    // shuffles issued by ALL lanes (sources must be active)
    float n0 = __shfl_down(a0, 8), n1 = __shfl_down(a1, 8),
          n2 = __shfl_down(a2, 8), n3 = __shfl_down(a3, 8),
          n4 = __shfl_down(a4, 8);
    if (edge) {
      n0 = cb[oc * 5 + 0]; n1 = cb[oc * 5 + 1]; n2 = cb[oc * 5 + 2];
      n3 = cb[oc * 5 + 3]; n4 = cb[oc * 5 + 4];
    }
    if (wr_ok) {
      float* orow = out + ((size_t)(b * 6 + oc) * 123 + p0) * 123;
      float m0 = fmaxf(fmaxf(fmaxf(a0, a1), fmaxf(n0, n1)), 0.f);
      float m1 = fmaxf(fmaxf(fmaxf(a1, a2), fmaxf(n1, n2)), 0.f);
      float m2 = fmaxf(fmaxf(fmaxf(a2, a3), fmaxf(n2, n3)), 0.f);
      float m3 = fmaxf(fmaxf(fmaxf(a3, a4), fmaxf(n3, n4)), 0.f);
      if (c0 + 3 < 123) {
        *(float4*)&orow[c0] = make_float4(m0, m1, m2, m3);
      } else {
        if (c0 < 123) orow[c0] = m0;
        if (c0 + 1 < 123) orow[c0 + 1] = m1;
        if (c0 + 2 < 123) orow[c0 + 2] = m2;
      }
    }
  }
}

// ---------------- Kernel 2: conv2 + relu + maxpool(2,s1) -------------------
// pool1 [128,6,123,123] -> act [128, 15*61*61] (NCHW flatten)
// (unchanged)
#define C2_ST 84
#define C2_TOT (35 * 67)    // 2345
__global__ __launch_bounds__(256) void conv2_pool_kernel(
    const float* __restrict__ in, const float* __restrict__ w,
    const float* __restrict__ bias, float* __restrict__ out) {
  const int b = blockIdx.z;
  const int P0 = blockIdx.x * 32;
  const int R0 = blockIdx.y * 16;
  const int tid = threadIdx.x;
  const int t = tid >> 4;           // pooled row 0..15
  const int s = tid & 15;           // strip 0..15 (2 pooled cols)

  __shared__ float lds[35 * C2_ST];

  const int ihb = 2 * R0 - 1, iwb = 2 * P0 - 1;
  const int r = R0 + t;
  const int c0 = P0 + 2 * s;

#pragma unroll 1
  for (int ocg = 0; ocg < 2; ocg++) {
    const int oc0 = ocg * 7;        // {0..7}, {7..14}
    float acc0[3][8], acc1[3][8];
#pragma unroll
    for (int k = 0; k < 8; k++) {
      float bv = bias[oc0 + k];
#pragma unroll
      for (int dc = 0; dc < 3; dc++) { acc0[dc][k] = bv; acc1[dc][k] = bv; }
    }

#pragma unroll 1
    for (int ci = 0; ci < 6; ci++) {
      __syncthreads();               // WAR
      const float* src = in + (size_t)(b * 6 + ci) * 15129;  // 123*123
#pragma unroll 1
      for (int base = tid; base < C2_TOT; base += 2048) {
        float vv[8];
        int lrv[8], ilv[8];
#pragma unroll
        for (int k = 0; k < 8; k++) {
          int i = base + (k << 8);
          int lr = (int)(((unsigned)i * 125204u) >> 23);  // i / 67
          int il = i - lr * 67;                           // i % 67
          lrv[k] = lr; ilv[k] = il;
          int ih = ihb + lr, iw = iwb + il;
          bool ok = (i < C2_TOT) && ((unsigned)ih < 123u) && ((unsigned)iw < 123u);
          vv[k] = ok ? src[ih * 123 + iw] : 0.f;
        }
#pragma unroll
        for (int k = 0; k < 8; k++) {
          int i = base + (k << 8);
          if (i < C2_TOT) lds[lrv[k] * C2_ST + ilv[k] + (ilv[k] >> 2)] = vv[k];
        }
      }
      __syncthreads();               // RAW

#pragma unroll 1
      for (int ir = 0; ir < 5; ir++) {
        const float* rp = &lds[(2 * t + ir) * C2_ST + 5 * s];
        float v[7];
#pragma unroll
        for (int j = 0; j < 7; j++) v[j] = rp[j + (j >> 2)];

        if (ir < 3) {                // conv row r, kh = ir
#pragma unroll
          for (int k = 0; k < 8; k++) {
            const float* wr = w + (((oc0 + k) * 6 + ci) * 3 + ir) * 3;
            float w0 = wr[0], w1 = wr[1], w2 = wr[2];
#pragma unroll
            for (int dc = 0; dc < 3; dc++) {
              float a = acc0[dc][k];
              a += w0 * v[2 * dc + 0];
              a += w1 * v[2 * dc + 1];
              a += w2 * v[2 * dc + 2];
              acc0[dc][k] = a;
            }
          }
        }
        if (ir >= 2) {               // conv row r+1, kh = ir-2
#pragma unroll
          for (int k = 0; k < 8; k++) {
            const float* wr = w + (((oc0 + k) * 6 + ci) * 3 + (ir - 2)) * 3;
            float w0 = wr[0], w1 = wr[1], w2 = wr[2];
#pragma unroll
            for (int dc = 0; dc < 3; dc++) {
              float a = acc1[dc][k];
              a += w0 * v[2 * dc + 0];
              a += w1 * v[2 * dc + 1];
              a += w2 * v[2 * dc + 2];
              acc1[dc][k] = a;
            }
          }
        }
      }
    }

    if (r < 61) {
#pragma unroll
      for (int k = 0; k < 8; k++) {
        int oc = oc0 + k;
        float* orow = out + ((size_t)(b * 15 + oc) * 61 + r) * 61;
        float m0 = fmaxf(fmaxf(fmaxf(acc0[0][k], acc0[1][k]),
                               fmaxf(acc1[0][k], acc1[1][k])), 0.f);
        float m1 = fmaxf(fmaxf(fmaxf(acc0[1][k], acc0[2][k]),
                               fmaxf(acc1[1][k], acc1[2][k])), 0.f);
        if (c0 + 1 < 61) {
          *(float2*)&orow[c0] = make_float2(m0, m1);
        } else if (c0 < 61) {
          orow[c0] = m0;
        }
      }
    }
  }
}

// ---------------- Kernel 3: fc1 split-K GEMM partials ----------------------
// (unchanged)
#define KTOT 55815
#define NPART 512
#define KCHUNK 112
__global__ __launch_bounds__(512) void fc1_splitk_kernel(
    const float* __restrict__ act, const float* __restrict__ w,
    float* __restrict__ partial) {
  const int kbase = blockIdx.x * KCHUNK;
  const int tid = threadIdx.x;
  const int tx = tid & 31, ty = tid >> 5;
  __shared__ float ldsA[8 * 132];
  __shared__ float ldsB[8 * 132];
  float acc[8][4];
#pragma unroll
  for (int i = 0; i < 8; i++)
#pragma unroll
    for (int j = 0; j < 4; j++) acc[i][j] = 0.f;

  for (int s8 = 0; s8 < KCHUNK / 8; s8++) {
    int kofs = kbase + s8 * 8;
    __syncthreads();
    for (int i = tid; i < 1024; i += 512) {
      int m = i >> 3, kk = i & 7;
      int k = kofs + kk;
      ldsA[kk * 132 + m] = (k < KTOT) ? act[m * KTOT + k] : 0.f;
    }
    for (int i = tid; i < 960; i += 512) {
      int n = i >> 3, kk = i & 7;
      int k = kofs + kk;
      ldsB[kk * 132 + n] = (k < KTOT) ? w[n * KTOT + k] : 0.f;
    }
    __syncthreads();
#pragma unroll
    for (int kk = 0; kk < 8; kk++) {
      float4 a0 = *(const float4*)&ldsA[kk * 132 + ty * 8];
      float4 a1 = *(const float4*)&ldsA[kk * 132 + ty * 8 + 4];
      float4 b0 = *(const float4*)&ldsB[kk * 132 + tx * 4];
      float av[8] = {a0.x, a0.y, a0.z, a0.w, a1.x, a1.y, a1.z, a1.w};
      float bv[4] = {b0.x, b0.y, b0.z, b0.w};
#pragma unroll
      for (int i = 0; i < 8; i++)
#pragma unroll
        for (int j = 0; j < 4; j++) acc[i][j] += av[i] * bv[j];
    }
  }

  if (tx < 30) {
    float* dst = partial + (size_t)blockIdx.x * 15360;
#pragma unroll
    for (int i = 0; i < 8; i++) {
      int row = ty * 8 + i;
      float4 st = make_float4(acc[i][0], acc[i][1], acc[i][2], acc[i][3]);
      *(float4*)&dst[row * 120 + tx * 4] = st;
    }
  }
}

// ---------------- Kernel 4: fused reduce (512 partials) + bias + relu ------
// partial [512][15360] -> h1 [15360].  Block: 256 thr = 8 p-groups x 32 idx.
// Thread (g, il) sums p = g, g+8, ..., g+504 for idx = blk*32+il (coalesced:
// 32 consecutive floats per (p, g) step). LDS 8x32 tree finishes.
__global__ __launch_bounds__(256) void fc1_reduce_kernel(
    const float* __restrict__ partial, const float* __restrict__ bias,
    float* __restrict__ h1) {
  const int g = threadIdx.x >> 5, il = threadIdx.x & 31;
  const int idx = blockIdx.x * 32 + il;
  const float* p = partial + (size_t)g * 15360 + idx;
  float s = 0.f;
#pragma unroll 8
  for (int q = 0; q < 64; q++) s += p[(size_t)(q * 8) * 15360];
  __shared__ float red[8][32];
  red[g][il] = s;
  __syncthreads();
  if (threadIdx.x < 32) {
    float tsum = 0.f;
#pragma unroll
    for (int gg = 0; gg < 8; gg++) tsum += red[gg][threadIdx.x];
    h1[idx] = fmaxf(tsum + bias[idx % 120], 0.f);
  }
}

// ---------------- Kernel 5: fc2 + fc3 + RBF + sigmoid ----------------------
__global__ __launch_bounds__(128) void head_kernel(
    const float* __restrict__ h1, const float* __restrict__ fc2_w,
    const float* __restrict__ fc2_b, const float* __restrict__ fc3_w,
    const float* __restrict__ fc3_b, const float* __restrict__ support,
    float* __restrict__ out) {
  int b = blockIdx.x, t = threadIdx.x;
  __shared__ float hrow[120];
  __shared__ float s2[84];
  if (t < 120) hrow[t] = h1[b * 120 + t];
  __syncthreads();
  if (t < 84) {
    float d = fc2_b[t];
    for (int k = 0; k < 120; k++) d += fc2_w[t * 120 + k] * hrow[k];
    s2[t] = fmaxf(d, 0.f);
  }
  __syncthreads();
  if (t == 0) {
    float h = fc3_b[0];
    for (int j = 0; j < 84; j++) h += fc3_w[j] * s2[j];
    float ks = 0.f;
    for (int j = 0; j < 10; j++) {
      float diff = h - support[j];
      ks += expf(-diff * diff);
    }
    ks *= 0.1f;
    float p = 1.f / (1.f + expf(-ks));
    out[b * 2] = p;
    out[b * 2 + 1] = 1.f - p;
  }
}

// ---------------------------------------------------------------------------
extern "C" void kernel_launch(void* const* d_in, const int* in_sizes, int n_in,
                              void* d_out, int out_size, void* d_ws, size_t ws_size,
                              hipStream_t stream) {
  const float* x   = (const float*)d_in[0];
  const float* c1w = (const float*)d_in[1];
  const float* c1b = (const float*)d_in[2];
  const float* c2w = (const float*)d_in[3];
  const float* c2b = (const float*)d_in[4];
  const float* f1w = (const float*)d_in[5];
  const float* f1b = (const float*)d_in[6];
  const float* f2w = (const float*)d_in[7];
  const float* f2b = (const float*)d_in[8];
  const float* f3w = (const float*)d_in[9];
  const float* f3b = (const float*)d_in[10];
  const float* sup = (const float*)d_in[11];
  float* out = (float*)d_out;

  char* ws = (char*)d_ws;
  // Lifetimes: pool1 [0,46.5MB) dead after conv2 -> part/h1 reuse it.
  float* pool1 = (float*)ws;                     // 46,476,288 B
  float* act   = (float*)(ws + 46476288);        // 28,577,280 B (alive thru fc1)
  float* part  = (float*)ws;                     // 512*15360*4 = 31,457,280 B
  float* h1    = (float*)(ws + 33000000);        //     61,440 B

  conv1_pool_kernel<<<dim3(4, 4, BATCH), 256, 0, stream>>>(x, c1w, c1b, pool1);
  conv2_pool_kernel<<<dim3(2, 4, BATCH), 256, 0, stream>>>(pool1, c2w, c2b, act);
  fc1_splitk_kernel<<<NPART, 512, 0, stream>>>(act, f1w, part);
  fc1_reduce_kernel<<<480, 256, 0, stream>>>(part, f1b, h1);
  head_kernel<<<BATCH, 128, 0, stream>>>(h1, f2w, f2b, f3w, f3b, sup, out);
}

// Round 6
// 326.702 us; speedup vs baseline: 2.5825x; 1.0708x over previous
//
#include <hip/hip_runtime.h>
#include <math.h>

// ---------------------------------------------------------------------------
// HybridBinaryClassifier360: conv1(3->6,5x5,s2,p1)+relu+maxpool2s1 ->
// conv2(6->15,3x3,s2,p1)+relu+maxpool2s1 -> fc 55815->120->84->1 ->
// RBF kernel vs 10 supports -> sigmoid -> [p, 1-p].  B=128, fp32.
//
// R15: conv1 untouched (R14-verified 92.6us; bank-constant tuning proven
// dead-end -- conflict counter identical across two address maps).
// conv2: ocg passes MERGED (acc 90 floats, ~120 VGPR natural, no pin) ->
// staging VALU and pool1 HBM re-reads halved, dup oc=7 compute removed.
// fc1: K-step 8->16 (barriers 28->14/block) + float4 A staging; act is now
// written with padded row stride KPAD=55816 (16B-aligned rows) by conv2.
// Reduce stays fused (R14 win). head unchanged.
// ---------------------------------------------------------------------------

#define BATCH 128
#define KPAD 55816              // act row stride (floats); 16B-aligned rows

// ---------------- Kernel 1: conv1 + relu + maxpool(2,s1) -------------------
// (EXACT R14 kernel -- verified 92.6us, 76 VGPR, no spill)
#define C1_ST 78
#define C1_COLS 69
#define C1_ROWS 67
#define C1_TOT (C1_ROWS * C1_COLS)   // 4623
__global__ __launch_bounds__(256) void conv1_pool_kernel(
    const float* __restrict__ x, const float* __restrict__ w,
    const float* __restrict__ bias, float* __restrict__ out) {
  const int b = blockIdx.z;
  const int P0 = blockIdx.x * 32;    // first pooled col
  const int R0 = blockIdx.y * 31;    // first pooled row
  const int tid = threadIdx.x;
  const int t = tid >> 3;            // rowgroup 0..31 (conv row R0+t)
  const int s = tid & 7;             // strip 0..7 (4 pooled cols)

  __shared__ float lds[C1_ROWS * C1_ST];   // 5226 floats = 20904 B
  float* cbuf = lds;                 // exchange reuses [0,720) after compute

  float acc[5][6];                   // conv row R0+t x 5 conv cols x 6 oc
#pragma unroll
  for (int oc = 0; oc < 6; oc++) {
    float bv = bias[oc];
#pragma unroll
    for (int dc = 0; dc < 5; dc++) acc[dc][oc] = bv;
  }

  const int ihb = 2 * R0 - 1, iwb = 2 * P0 - 1;

#pragma unroll 1
  for (int ci = 0; ci < 3; ci++) {
    __syncthreads();                 // WAR: previous ci's compute done
    const float* src = x + (size_t)(b * 3 + ci) * 62500;
#pragma unroll 1
    for (int base = tid; base < C1_TOT; base += 1024) {
      float vv[4];
      int lrv[4], ilv[4];
#pragma unroll
      for (int k = 0; k < 4; k++) {
        int i = base + (k << 8);
        int lr = (int)(((unsigned)i * 121575u) >> 23);  // i / 69
        int il = i - lr * 69;                           // i % 69
        lrv[k] = lr; ilv[k] = il;
        int ih = ihb + lr, iw = iwb + il;
        bool ok = (i < C1_TOT) && ((unsigned)ih < 250u) && ((unsigned)iw < 250u);
        vv[k] = ok ? src[ih * 250 + iw] : 0.f;
      }
#pragma unroll
      for (int k = 0; k < 4; k++) {
        int i = base + (k << 8);
        if (i < C1_TOT) lds[lrv[k] * C1_ST + ilv[k] + (ilv[k] >> 3)] = vv[k];
      }
    }
    __syncthreads();                 // RAW: staging visible

    const float* rbase = &lds[(2 * t) * C1_ST + 9 * s];
#pragma unroll
    for (int ir = 0; ir < 5; ir++) {
      const float* rpl = rbase + ir * C1_ST;
      const float* rph = rpl + 1;
      float v[13];
#pragma unroll
      for (int j = 0; j < 8; j++)  v[j] = rpl[j];
#pragma unroll
      for (int j = 8; j < 13; j++) v[j] = rph[j];
#pragma unroll
      for (int oc = 0; oc < 6; oc++) {
        const float* wr = w + ((oc * 3 + ci) * 5 + ir) * 5;
        float w0 = wr[0], w1 = wr[1], w2 = wr[2], w3 = wr[3], w4 = wr[4];
#pragma unroll
        for (int dc = 0; dc < 5; dc++) {
          float a = acc[dc][oc];
          a += w0 * v[2 * dc + 0];
          a += w1 * v[2 * dc + 1];
          a += w2 * v[2 * dc + 2];
          a += w3 * v[2 * dc + 3];
          a += w4 * v[2 * dc + 4];
          acc[dc][oc] = a;
        }
      }
    }
  }

  // ---- wave-boundary exchange: conv rows 8/16/24 publish for t=7/15/23 ----
  __syncthreads();                   // all compute done; input slice dead
  if (t == 8 || t == 16 || t == 24) {
    float* cb = &cbuf[(((t >> 3) - 1) * 8 + s) * 30];
#pragma unroll
    for (int oc = 0; oc < 6; oc++)
#pragma unroll
      for (int dc = 0; dc < 5; dc++) cb[oc * 5 + dc] = acc[dc][oc];
  }
  __syncthreads();                   // cbuf visible

  const int p0 = R0 + t;
  const int c0 = P0 + 4 * s;
  const bool edge = ((t & 7) == 7) && (t < 31);   // neighbor is cross-wave
  const bool wr_ok = (t < 31) && (p0 < 123);
  const float* cb = &cbuf[((t >> 3) * 8 + s) * 30];

#pragma unroll
  for (int oc = 0; oc < 6; oc++) {
    float a0 = acc[0][oc], a1 = acc[1][oc], a2 = acc[2][oc],
          a3 = acc[3][oc], a4 = acc[4][oc];
    float n0 = __shfl_down(a0, 8), n1 = __shfl_down(a1, 8),
          n2 = __shfl_down(a2, 8), n3 = __shfl_down(a3, 8),
          n4 = __shfl_down(a4, 8);
    if (edge) {
      n0 = cb[oc * 5 + 0]; n1 = cb[oc * 5 + 1]; n2 = cb[oc * 5 + 2];
      n3 = cb[oc * 5 + 3]; n4 = cb[oc * 5 + 4];
    }
    if (wr_ok) {
      float* orow = out + ((size_t)(b * 6 + oc) * 123 + p0) * 123;
      float m0 = fmaxf(fmaxf(fmaxf(a0, a1), fmaxf(n0, n1)), 0.f);
      float m1 = fmaxf(fmaxf(fmaxf(a1, a2), fmaxf(n1, n2)), 0.f);
      float m2 = fmaxf(fmaxf(fmaxf(a2, a3), fmaxf(n2, n3)), 0.f);
      float m3 = fmaxf(fmaxf(fmaxf(a3, a4), fmaxf(n3, n4)), 0.f);
      if (c0 + 3 < 123) {
        *(float4*)&orow[c0] = make_float4(m0, m1, m2, m3);
      } else {
        if (c0 < 123) orow[c0] = m0;
        if (c0 + 1 < 123) orow[c0 + 1] = m1;
        if (c0 + 2 < 123) orow[c0 + 2] = m2;
      }
    }
  }
}

// ---------------- Kernel 2: conv2 + relu + maxpool(2,s1) -------------------
// pool1 [128,6,123,123] -> act [128][KPAD] (k = oc*3721 + r*61 + c, padded)
// R15: single pass over all 15 oc (acc 90 floats). Staging once per ci
// (halves staging + pool1 refetch vs the 2-ocg version). Batch-4 staging
// keeps the live set under the 128-VGPR cliff; NO launch-bounds pin.
#define C2_ST 84
#define C2_TOT (35 * 67)    // 2345
__global__ __launch_bounds__(256) void conv2_pool_kernel(
    const float* __restrict__ in, const float* __restrict__ w,
    const float* __restrict__ bias, float* __restrict__ out) {
  const int b = blockIdx.z;
  const int P0 = blockIdx.x * 32;
  const int R0 = blockIdx.y * 16;
  const int tid = threadIdx.x;
  const int t = tid >> 4;           // pooled row 0..15
  const int s = tid & 15;           // strip 0..15 (2 pooled cols)

  __shared__ float lds[35 * C2_ST];

  const int ihb = 2 * R0 - 1, iwb = 2 * P0 - 1;
  const int r = R0 + t;
  const int c0 = P0 + 2 * s;

  float acc0[3][15], acc1[3][15];   // conv rows r, r+1 x 3 conv cols x 15 oc
#pragma unroll
  for (int oc = 0; oc < 15; oc++) {
    float bv = bias[oc];
#pragma unroll
    for (int dc = 0; dc < 3; dc++) { acc0[dc][oc] = bv; acc1[dc][oc] = bv; }
  }

#pragma unroll 1
  for (int ci = 0; ci < 6; ci++) {
    __syncthreads();               // WAR
    const float* src = in + (size_t)(b * 6 + ci) * 15129;  // 123*123
#pragma unroll 1
    for (int base = tid; base < C2_TOT; base += 1024) {
      float vv[4];
      int ladr[4];
#pragma unroll
      for (int k = 0; k < 4; k++) {
        int i = base + (k << 8);
        int lr = (int)(((unsigned)i * 125204u) >> 23);  // i / 67
        int il = i - lr * 67;                           // i % 67
        int ih = ihb + lr, iw = iwb + il;
        bool ok = (i < C2_TOT) && ((unsigned)ih < 123u) && ((unsigned)iw < 123u);
        vv[k] = ok ? src[ih * 123 + iw] : 0.f;
        ladr[k] = (i < C2_TOT) ? (lr * C2_ST + il + (il >> 2)) : -1;
      }
#pragma unroll
      for (int k = 0; k < 4; k++) {
        if (ladr[k] >= 0) lds[ladr[k]] = vv[k];
      }
    }
    __syncthreads();               // RAW

#pragma unroll 1
    for (int ir = 0; ir < 5; ir++) {
      const float* rp = &lds[(2 * t + ir) * C2_ST + 5 * s];
      float v[7];
#pragma unroll
      for (int j = 0; j < 7; j++) v[j] = rp[j + (j >> 2)];

      if (ir < 3) {                // conv row r, kh = ir
#pragma unroll
        for (int oc = 0; oc < 15; oc++) {
          const float* wr = w + ((oc * 6 + ci) * 3 + ir) * 3;
          float w0 = wr[0], w1 = wr[1], w2 = wr[2];
#pragma unroll
          for (int dc = 0; dc < 3; dc++) {
            float a = acc0[dc][oc];
            a += w0 * v[2 * dc + 0];
            a += w1 * v[2 * dc + 1];
            a += w2 * v[2 * dc + 2];
            acc0[dc][oc] = a;
          }
        }
      }
      if (ir >= 2) {               // conv row r+1, kh = ir-2
#pragma unroll
        for (int oc = 0; oc < 15; oc++) {
          const float* wr = w + ((oc * 6 + ci) * 3 + (ir - 2)) * 3;
          float w0 = wr[0], w1 = wr[1], w2 = wr[2];
#pragma unroll
          for (int dc = 0; dc < 3; dc++) {
            float a = acc1[dc][oc];
            a += w0 * v[2 * dc + 0];
            a += w1 * v[2 * dc + 1];
            a += w2 * v[2 * dc + 2];
            acc1[dc][oc] = a;
          }
        }
      }
    }
  }

  if (r < 61) {
#pragma unroll
    for (int oc = 0; oc < 15; oc++) {
      float* orow = out + (size_t)b * KPAD + (oc * 3721 + r * 61);
      float m0 = fmaxf(fmaxf(fmaxf(acc0[0][oc], acc0[1][oc]),
                             fmaxf(acc1[0][oc], acc1[1][oc])), 0.f);
      float m1 = fmaxf(fmaxf(fmaxf(acc0[1][oc], acc0[2][oc]),
                             fmaxf(acc1[1][oc], acc1[2][oc])), 0.f);
      if (c0 + 1 < 61) {
        *(float2*)&orow[c0] = make_float2(m0, m1);
      } else if (c0 < 61) {
        orow[c0] = m0;
      }
    }
  }
}

// ---------------- Kernel 3: fc1 split-K GEMM partials ----------------------
// act [128][KPAD] x fc1_w [120][KTOT] -> partial [NPART][15360]
// R15: K-step 8->16 (barriers 28->14), A staged as aligned float4 (KPAD
// rows are 16B-aligned). B (input w, odd stride) stays scalar, 16-wide
// coalesced rows.
#define KTOT 55815
#define NPART 512
#define KCHUNK 112
#define KSTEP 16
__global__ __launch_bounds__(512) void fc1_splitk_kernel(
    const float* __restrict__ act, const float* __restrict__ w,
    float* __restrict__ partial) {
  const int kbase = blockIdx.x * KCHUNK;
  const int tid = threadIdx.x;
  const int tx = tid & 31, ty = tid >> 5;
  __shared__ float ldsA[KSTEP * 132];
  __shared__ float ldsB[KSTEP * 132];
  float acc[8][4];
#pragma unroll
  for (int i = 0; i < 8; i++)
#pragma unroll
    for (int j = 0; j < 4; j++) acc[i][j] = 0.f;

  const int mA = tid >> 2;            // 0..127
  const int qA = (tid & 3) * 4;       // k offset within step: 0,4,8,12

  for (int s16 = 0; s16 < KCHUNK / KSTEP; s16++) {
    int kofs = kbase + s16 * KSTEP;
    __syncthreads();
    { // ---- A: 128 rows x 16 k = 2048 floats = 512 aligned float4 ----
      int k = kofs + qA;
      float4 a4;
      if (k + 3 < KTOT) {
        a4 = *(const float4*)&act[(size_t)mA * KPAD + k];
      } else {
        a4.x = (k + 0 < KTOT) ? act[(size_t)mA * KPAD + k + 0] : 0.f;
        a4.y = (k + 1 < KTOT) ? act[(size_t)mA * KPAD + k + 1] : 0.f;
        a4.z = (k + 2 < KTOT) ? act[(size_t)mA * KPAD + k + 2] : 0.f;
        a4.w = (k + 3 < KTOT) ? act[(size_t)mA * KPAD + k + 3] : 0.f;
      }
      ldsA[(qA + 0) * 132 + mA] = a4.x;
      ldsA[(qA + 1) * 132 + mA] = a4.y;
      ldsA[(qA + 2) * 132 + mA] = a4.z;
      ldsA[(qA + 3) * 132 + mA] = a4.w;
    }
    // ---- B: 120 rows x 16 k = 1920 floats, scalar coalesced ----
    for (int i = tid; i < 1920; i += 512) {
      int n = i >> 4, kk = i & 15;
      int k = kofs + kk;
      ldsB[kk * 132 + n] = (k < KTOT) ? w[n * KTOT + k] : 0.f;
    }
    __syncthreads();
#pragma unroll
    for (int kk = 0; kk < KSTEP; kk++) {
      float4 a0 = *(const float4*)&ldsA[kk * 132 + ty * 8];
      float4 a1 = *(const float4*)&ldsA[kk * 132 + ty * 8 + 4];
      float4 b0 = *(const float4*)&ldsB[kk * 132 + tx * 4];
      float av[8] = {a0.x, a0.y, a0.z, a0.w, a1.x, a1.y, a1.z, a1.w};
      float bv[4] = {b0.x, b0.y, b0.z, b0.w};
#pragma unroll
      for (int i = 0; i < 8; i++)
#pragma unroll
        for (int j = 0; j < 4; j++) acc[i][j] += av[i] * bv[j];
    }
  }

  if (tx < 30) {
    float* dst = partial + (size_t)blockIdx.x * 15360;
#pragma unroll
    for (int i = 0; i < 8; i++) {
      int row = ty * 8 + i;
      float4 st = make_float4(acc[i][0], acc[i][1], acc[i][2], acc[i][3]);
      *(float4*)&dst[row * 120 + tx * 4] = st;
    }
  }
}

// ---------------- Kernel 4: fused reduce (512 partials) + bias + relu ------
// partial [512][15360] -> h1 [15360].  Block: 256 thr = 8 p-groups x 32 idx.
__global__ __launch_bounds__(256) void fc1_reduce_kernel(
    const float* __restrict__ partial, const float* __restrict__ bias,
    float* __restrict__ h1) {
  const int g = threadIdx.x >> 5, il = threadIdx.x & 31;
  const int idx = blockIdx.x * 32 + il;
  const float* p = partial + (size_t)g * 15360 + idx;
  float s = 0.f;
#pragma unroll 8
  for (int q = 0; q < 64; q++) s += p[(size_t)(q * 8) * 15360];
  __shared__ float red[8][32];
  red[g][il] = s;
  __syncthreads();
  if (threadIdx.x < 32) {
    float tsum = 0.f;
#pragma unroll
    for (int gg = 0; gg < 8; gg++) tsum += red[gg][threadIdx.x];
    h1[idx] = fmaxf(tsum + bias[idx % 120], 0.f);
  }
}

// ---------------- Kernel 5: fc2 + fc3 + RBF + sigmoid ----------------------
__global__ __launch_bounds__(128) void head_kernel(
    const float* __restrict__ h1, const float* __restrict__ fc2_w,
    const float* __restrict__ fc2_b, const float* __restrict__ fc3_w,
    const float* __restrict__ fc3_b, const float* __restrict__ support,
    float* __restrict__ out) {
  int b = blockIdx.x, t = threadIdx.x;
  __shared__ float hrow[120];
  __shared__ float s2[84];
  if (t < 120) hrow[t] = h1[b * 120 + t];
  __syncthreads();
  if (t < 84) {
    float d = fc2_b[t];
    for (int k = 0; k < 120; k++) d += fc2_w[t * 120 + k] * hrow[k];
    s2[t] = fmaxf(d, 0.f);
  }
  __syncthreads();
  if (t == 0) {
    float h = fc3_b[0];
    for (int j = 0; j < 84; j++) h += fc3_w[j] * s2[j];
    float ks = 0.f;
    for (int j = 0; j < 10; j++) {
      float diff = h - support[j];
      ks += expf(-diff * diff);
    }
    ks *= 0.1f;
    float p = 1.f / (1.f + expf(-ks));
    out[b * 2] = p;
    out[b * 2 + 1] = 1.f - p;
  }
}

// ---------------------------------------------------------------------------
extern "C" void kernel_launch(void* const* d_in, const int* in_sizes, int n_in,
                              void* d_out, int out_size, void* d_ws, size_t ws_size,
                              hipStream_t stream) {
  const float* x   = (const float*)d_in[0];
  const float* c1w = (const float*)d_in[1];
  const float* c1b = (const float*)d_in[2];
  const float* c2w = (const float*)d_in[3];
  const float* c2b = (const float*)d_in[4];
  const float* f1w = (const float*)d_in[5];
  const float* f1b = (const float*)d_in[6];
  const float* f2w = (const float*)d_in[7];
  const float* f2b = (const float*)d_in[8];
  const float* f3w = (const float*)d_in[9];
  const float* f3b = (const float*)d_in[10];
  const float* sup = (const float*)d_in[11];
  float* out = (float*)d_out;

  char* ws = (char*)d_ws;
  // Lifetimes: pool1 [0,46.5MB) dead after conv2 -> part/h1 reuse it.
  float* pool1 = (float*)ws;                     // 46,476,288 B
  float* act   = (float*)(ws + 46476288);        // 128*KPAD*4 = 28,577,792 B
  float* part  = (float*)ws;                     // 512*15360*4 = 31,457,280 B
  float* h1    = (float*)(ws + 33000000);        //     61,440 B

  conv1_pool_kernel<<<dim3(4, 4, BATCH), 256, 0, stream>>>(x, c1w, c1b, pool1);
  conv2_pool_kernel<<<dim3(2, 4, BATCH), 256, 0, stream>>>(pool1, c2w, c2b, act);
  fc1_splitk_kernel<<<NPART, 512, 0, stream>>>(act, f1w, part);
  fc1_reduce_kernel<<<480, 256, 0, stream>>>(part, f1b, h1);
  head_kernel<<<BATCH, 128, 0, stream>>>(h1, f2w, f2b, f3w, f3b, sup, out);
}